// Round 9
// baseline (499.094 us; speedup 1.0000x reference)
//
#include <hip/hip_runtime.h>
#include <hip/hip_cooperative_groups.h>
#include <math.h>

namespace cg = cooperative_groups;

#define D_FEAT 64
#define SCAN_BLOCK 1024
#define NG 8          // edge groups (private counters, one per XCD)
#define NR 8          // dst ranges (XCD-local scatter writes)

// ---------------------------------------------------------------------------
// ws layout (ints):
//   priv       : NG * n_nodes   (counts -> cross-group relative prefixes -> cursors)
//   offsets    : n_nodes + 1
//   blocksums  : 1024
//   sorted_src : n_edges
// ---------------------------------------------------------------------------

// wave-shuffle block exclusive scan; requires blockDim.x == 1024
__device__ __forceinline__ int block_scan_excl_1024(int v, int* smem16) {
    int lane = threadIdx.x & 63;
    int wid  = threadIdx.x >> 6;
    int x = v;
    #pragma unroll
    for (int d = 1; d < 64; d <<= 1) {
        int t = __shfl_up(x, d, 64);
        if (lane >= d) x += t;
    }
    if (lane == 63) smem16[wid] = x;          // wave inclusive totals
    __syncthreads();
    if (wid == 0) {
        int s = (lane < 16) ? smem16[lane] : 0;
        #pragma unroll
        for (int d = 1; d < 16; d <<= 1) {
            int t = __shfl_up(s, d, 64);
            if (lane >= d) s += t;
        }
        if (lane < 16) smem16[lane] = s;      // inclusive scan of wave totals
    }
    __syncthreads();
    int base = (wid > 0) ? smem16[wid - 1] : 0;
    return base + x - v;                      // exclusive prefix
}

// ======================= fused cooperative CSR build =======================

__global__ __launch_bounds__(1024, 8)
void build_csr_coop(const int* __restrict__ src, const int* __restrict__ dst,
                    int* __restrict__ priv, int* __restrict__ offsets,
                    int* __restrict__ blocksums, int* __restrict__ sorted_src,
                    int n_nodes, int n_edges, int egroup, int nodes_per_range,
                    int ntiles) {
    cg::grid_group grid = cg::this_grid();
    __shared__ int smem16[16];
    const int tid = threadIdx.x;
    const int bid = blockIdx.x;
    const int nb  = gridDim.x;           // multiple of 64

    // phase 0: zero priv
    {
        int total = NG * n_nodes;
        for (int i = bid * SCAN_BLOCK + tid; i < total; i += nb * SCAN_BLOCK)
            priv[i] = 0;
    }
    grid.sync();

    // phase 1: count. group g (bid&7 -> XCD g) streams its contiguous 1/8 of
    // the edge list once, coalesced; atomics hit priv[g][*] (XCD-local L2).
    {
        int g = bid & (NG - 1);
        int c = bid >> 3;
        int nchunks = nb >> 3;
        int ebeg = g * egroup;
        int eend = ebeg + egroup; if (eend > n_edges) eend = n_edges;
        int* cnt = priv + (size_t)g * n_nodes;
        int stride = nchunks * SCAN_BLOCK;
        for (int e = ebeg + c * SCAN_BLOCK + tid; e < eend; e += stride)
            atomicAdd(&cnt[dst[e]], 1);
    }
    grid.sync();

    // phase 2: cross-group exclusive prefix (priv in place) + block scan of
    // node totals into offsets (tile-local) + blocksums.
    for (int tile = bid; tile < ntiles; tile += nb) {
        int i = tile * SCAN_BLOCK + tid;
        int total = 0;
        if (i < n_nodes) {
            int run = 0;
            #pragma unroll
            for (int g = 0; g < NG; ++g) {
                size_t idx = (size_t)g * n_nodes + i;
                int t = priv[idx];
                priv[idx] = run;      // relative sub-segment start
                run += t;
            }
            total = run;
        }
        int excl = block_scan_excl_1024(total, smem16);
        if (i < n_nodes) offsets[i] = excl;
        if (tid == SCAN_BLOCK - 1) blocksums[tile] = excl + total;
        __syncthreads();              // smem16 WAR before next tile
    }
    grid.sync();

    // phase 3: block 0 exclusive-scans blocksums (ntiles <= 1024)
    if (bid == 0) {
        int v = (tid < ntiles) ? blocksums[tid] : 0;
        int e = block_scan_excl_1024(v, smem16);
        if (tid < ntiles) blocksums[tid] = e;
    }
    grid.sync();

    // phase 4: add tile bases
    for (int tile = bid; tile < ntiles; tile += nb) {
        int i = tile * SCAN_BLOCK + tid;
        if (i < n_nodes) offsets[i] += blocksums[tile];
    }
    if (bid == 0 && tid == 0) offsets[n_nodes] = n_edges;
    grid.sync();

    // phase 5: scatter. block (r,g,c): r -> XCD r; cursor atomics and
    // sorted_src writes both land in XCD-r's L2.
    {
        int r = bid & (NR - 1);
        int g = (bid >> 3) & (NG - 1);
        int c = bid >> 6;
        int nchunks = nb >> 6;
        int lo = r * nodes_per_range;
        int hi = lo + nodes_per_range;
        int ebeg = g * egroup;
        int eend = ebeg + egroup; if (eend > n_edges) eend = n_edges;
        int* cur = priv + (size_t)g * n_nodes;
        int stride = nchunks * SCAN_BLOCK;
        for (int e = ebeg + c * SCAN_BLOCK + tid; e < eend; e += stride) {
            int d = dst[e];
            if (d >= lo && d < hi) {
                int pos = offsets[d] + atomicAdd(&cur[d], 1);
                sorted_src[pos] = src[e];
            }
        }
    }
}

// ==================== fallback multi-kernel build (R8) =====================

__global__ void count_group_kernel(const int* __restrict__ dst,
                                   int* __restrict__ priv,
                                   int n_nodes, int n_edges, int egroup) {
    int g = blockIdx.x & (NG - 1);
    int c = blockIdx.x >> 3;
    int nchunks = gridDim.x >> 3;
    int ebeg = g * egroup;
    int eend = ebeg + egroup; if (eend > n_edges) eend = n_edges;
    int* cnt = priv + (size_t)g * n_nodes;
    int stride = nchunks * blockDim.x;
    for (int e = ebeg + c * blockDim.x + threadIdx.x; e < eend; e += stride) {
        atomicAdd(&cnt[dst[e]], 1);
    }
}

__global__ void scanA_fused_kernel(int* __restrict__ priv,
                                   int* __restrict__ offsets,
                                   int* __restrict__ blocksums, int n_nodes) {
    __shared__ int smem16[16];
    int i = blockIdx.x * SCAN_BLOCK + threadIdx.x;
    int total = 0;
    if (i < n_nodes) {
        int run = 0;
        #pragma unroll
        for (int g = 0; g < NG; ++g) {
            size_t idx = (size_t)g * n_nodes + i;
            int t = priv[idx];
            priv[idx] = run;
            run += t;
        }
        total = run;
    }
    int excl = block_scan_excl_1024(total, smem16);
    if (i < n_nodes) offsets[i] = excl;
    if (threadIdx.x == SCAN_BLOCK - 1) blocksums[blockIdx.x] = excl + total;
}

__global__ void scanB_kernel(int* __restrict__ blocksums, int nb) {
    __shared__ int smem16[16];
    int v = ((int)threadIdx.x < nb) ? blocksums[threadIdx.x] : 0;
    int e = block_scan_excl_1024(v, smem16);
    if ((int)threadIdx.x < nb) blocksums[threadIdx.x] = e;
}

__global__ void scanC_kernel(int* __restrict__ offsets,
                             const int* __restrict__ blocksums,
                             int n, int n_edges) {
    int i = blockIdx.x * SCAN_BLOCK + threadIdx.x;
    if (i < n) offsets[i] += blocksums[blockIdx.x];
    if (i == 0) offsets[n] = n_edges;
}

__global__ void scatter_rg_kernel(const int* __restrict__ src,
                                  const int* __restrict__ dst,
                                  const int* __restrict__ offsets,
                                  int* __restrict__ priv,
                                  int* __restrict__ sorted_src,
                                  int n_nodes, int n_edges, int egroup,
                                  int nodes_per_range) {
    int r = blockIdx.x & (NR - 1);
    int g = (blockIdx.x >> 3) & (NG - 1);
    int c = blockIdx.x >> 6;
    int nchunks = gridDim.x >> 6;
    int lo = r * nodes_per_range;
    int hi = lo + nodes_per_range;
    int ebeg = g * egroup;
    int eend = ebeg + egroup; if (eend > n_edges) eend = n_edges;
    int* cur = priv + (size_t)g * n_nodes;
    int stride = nchunks * blockDim.x;
    for (int e = ebeg + c * blockDim.x + threadIdx.x; e < eend; e += stride) {
        int d = dst[e];
        if (d >= lo && d < hi) {
            int pos = offsets[d] + atomicAdd(&cur[d], 1);
            sorted_src[pos] = src[e];
        }
    }
}

// ============================== pull phase =================================

// one wave per node; 4 groups x 16 lanes, float4 gathers, 2-deep unroll.
__global__ void pull_max_kernel(const float* __restrict__ inp,
                                const int* __restrict__ offsets,
                                const int* __restrict__ sorted_src,
                                float* __restrict__ out, int n_nodes) {
    int gtid = blockIdx.x * blockDim.x + threadIdx.x;
    int node = gtid >> 6;
    if (node >= n_nodes) return;
    int lane = threadIdx.x & 63;
    int g = lane >> 4;
    int l = lane & 15;

    int beg = offsets[node];
    int end = offsets[node + 1];

    const float4* inp4 = reinterpret_cast<const float4*>(inp);
    float4 own = inp4[(size_t)node * 16 + l];

    float4 m;
    m.x = -INFINITY; m.y = -INFINITY; m.z = -INFINITY; m.w = -INFINITY;
    int j = beg + g;
    for (; j + 4 < end; j += 8) {
        int s0 = sorted_src[j];
        int s1 = sorted_src[j + 4];
        float4 v0 = inp4[(size_t)s0 * 16 + l];
        float4 v1 = inp4[(size_t)s1 * 16 + l];
        m.x = fmaxf(m.x, fmaxf(v0.x, v1.x));
        m.y = fmaxf(m.y, fmaxf(v0.y, v1.y));
        m.z = fmaxf(m.z, fmaxf(v0.z, v1.z));
        m.w = fmaxf(m.w, fmaxf(v0.w, v1.w));
    }
    if (j < end) {
        int s = sorted_src[j];
        float4 v = inp4[(size_t)s * 16 + l];
        m.x = fmaxf(m.x, v.x);
        m.y = fmaxf(m.y, v.y);
        m.z = fmaxf(m.z, v.z);
        m.w = fmaxf(m.w, v.w);
    }
    m.x = fmaxf(m.x, __shfl_xor(m.x, 16, 64));
    m.y = fmaxf(m.y, __shfl_xor(m.y, 16, 64));
    m.z = fmaxf(m.z, __shfl_xor(m.z, 16, 64));
    m.w = fmaxf(m.w, __shfl_xor(m.w, 16, 64));
    m.x = fmaxf(m.x, __shfl_xor(m.x, 32, 64));
    m.y = fmaxf(m.y, __shfl_xor(m.y, 32, 64));
    m.z = fmaxf(m.z, __shfl_xor(m.z, 32, 64));
    m.w = fmaxf(m.w, __shfl_xor(m.w, 32, 64));

    if (beg == end) m = own;   // isolated node keeps own feature

    float4* out4 = reinterpret_cast<float4*>(out);
    if (lane < 16) {
        out4[(size_t)node * 32 + l] = own;
    } else if (lane < 32) {
        out4[(size_t)node * 32 + 16 + l] = m;
    }
}

// ===========================================================================

extern "C" void kernel_launch(void* const* d_in, const int* in_sizes, int n_in,
                              void* d_out, int out_size, void* d_ws, size_t ws_size,
                              hipStream_t stream) {
    const float* inp = (const float*)d_in[0];
    const int* src = (const int*)d_in[1];
    const int* dst = (const int*)d_in[2];
    float* out = (float*)d_out;

    int n_nodes = in_sizes[0] / D_FEAT;
    int n_edges = in_sizes[1];

    int ntiles = (n_nodes + SCAN_BLOCK - 1) / SCAN_BLOCK;   // 98 for 100K
    int nodes_per_range = (n_nodes + NR - 1) / NR;
    int egroup = (n_edges + NG - 1) / NG;

    int* ws = (int*)d_ws;
    int* priv = ws;                                        // NG*n
    int* offsets = ws + (size_t)NG * n_nodes;              // n+1
    int* blocksums = offsets + n_nodes + 1;                // 1024
    int* sorted_src = blocksums + 1024;                    // E

    // ---- try fused cooperative build ----
    bool coop_done = false;
    if (ntiles <= 1024) {
        int maxB = 0;
        hipError_t qerr = hipOccupancyMaxActiveBlocksPerMultiprocessor(
            &maxB, build_csr_coop, SCAN_BLOCK, 0);
        if (qerr == hipSuccess && maxB > 0) {
            int nb = maxB * 256;          // 256 CUs on MI355X
            if (nb > 512) nb = 512;
            nb &= ~63;                    // multiple of 64 for (r,g,c) decomposition
            if (nb >= 64) {
                const int* a_src = src; const int* a_dst = dst;
                int* a_priv = priv; int* a_off = offsets;
                int* a_bs = blocksums; int* a_ss = sorted_src;
                int a_n = n_nodes, a_e = n_edges, a_eg = egroup;
                int a_npr = nodes_per_range, a_nt = ntiles;
                void* args[] = {(void*)&a_src, (void*)&a_dst, (void*)&a_priv,
                                (void*)&a_off, (void*)&a_bs, (void*)&a_ss,
                                (void*)&a_n, (void*)&a_e, (void*)&a_eg,
                                (void*)&a_npr, (void*)&a_nt};
                hipError_t lerr = hipLaunchCooperativeKernel(
                    (const void*)build_csr_coop, dim3(nb), dim3(SCAN_BLOCK),
                    args, 0, stream);
                coop_done = (lerr == hipSuccess);
            }
        }
    }

    if (!coop_done) {
        // ---- fallback: multi-kernel build (R8 path) ----
        hipMemsetAsync(priv, 0, (size_t)NG * n_nodes * sizeof(int), stream);
        count_group_kernel<<<NG * 256, 256, 0, stream>>>(dst, priv, n_nodes,
                                                         n_edges, egroup);
        scanA_fused_kernel<<<ntiles, SCAN_BLOCK, 0, stream>>>(priv, offsets,
                                                              blocksums, n_nodes);
        scanB_kernel<<<1, SCAN_BLOCK, 0, stream>>>(blocksums, ntiles);
        scanC_kernel<<<ntiles, SCAN_BLOCK, 0, stream>>>(offsets, blocksums,
                                                        n_nodes, n_edges);
        scatter_rg_kernel<<<NR * NG * 32, 256, 0, stream>>>(src, dst, offsets,
                                                            priv, sorted_src,
                                                            n_nodes, n_edges,
                                                            egroup, nodes_per_range);
    }

    // ---- pull-style segment max + concat ----
    {
        int total = n_nodes * 64;
        pull_max_kernel<<<(total + 255) / 256, 256, 0, stream>>>(
            inp, offsets, sorted_src, out, n_nodes);
    }
}

// Round 10
// 245.409 us; speedup vs baseline: 2.0337x; 2.0337x over previous
//
#include <hip/hip_runtime.h>
#include <math.h>

#define D_FEAT 64
#define SCAN_BLOCK 1024
#define NG 8          // edge groups (private counters, one per XCD)
#define NR 8          // dst ranges (XCD-local scatter writes)
// NOTE: this kernel assumes ntiles = ceil(n_nodes/1024) <= 128 (n <= 131072).
// Problem size is fixed at n=100000 (98 tiles).

// ---------------------------------------------------------------------------
// main ws layout (ints):
//   priv       : NG * n_nodes   (memset-zeroed; counts -> relative prefixes -> cursors)
//   offsets    : n_nodes + 1    (TILE-LOCAL exclusive prefixes)
//   blocksums  : 128            (RAW per-tile totals; consumers scan on the fly)
//   sorted_src : n_edges
// fallback ws: counts n | cursor n | offsets n+1 | blocksums 128 | sorted E
// ---------------------------------------------------------------------------

// wave-shuffle block exclusive scan; requires blockDim.x == 1024
__device__ __forceinline__ int block_scan_excl_1024(int v, int* smem16) {
    int lane = threadIdx.x & 63;
    int wid  = threadIdx.x >> 6;
    int x = v;
    #pragma unroll
    for (int d = 1; d < 64; d <<= 1) {
        int t = __shfl_up(x, d, 64);
        if (lane >= d) x += t;
    }
    if (lane == 63) smem16[wid] = x;
    __syncthreads();
    if (wid == 0) {
        int s = (lane < 16) ? smem16[lane] : 0;
        #pragma unroll
        for (int d = 1; d < 16; d <<= 1) {
            int t = __shfl_up(s, d, 64);
            if (lane >= d) s += t;
        }
        if (lane < 16) smem16[lane] = s;
    }
    __syncthreads();
    int base = (wid > 0) ? smem16[wid - 1] : 0;
    return base + x - v;
}

// build a 0..128 exclusive-prefix table of blocksums into LDS (one wave).
// pfx must be __shared__ int[130]. Call with all threads; barrier inside.
__device__ __forceinline__ void build_pfx_lds(const int* __restrict__ blocksums,
                                              int ntiles, int* pfx) {
    int tid = threadIdx.x;
    if (tid < 64) {
        int a = (tid < ntiles) ? blocksums[tid] : 0;
        int b = (tid + 64 < ntiles) ? blocksums[tid + 64] : 0;
        int A = a;
        #pragma unroll
        for (int d = 1; d < 64; d <<= 1) {
            int t = __shfl_up(A, d, 64);
            if (tid >= d) A += t;
        }
        int totalA = __shfl(A, 63, 64);
        int B = b;
        #pragma unroll
        for (int d = 1; d < 64; d <<= 1) {
            int t = __shfl_up(B, d, 64);
            if (tid >= d) B += t;
        }
        B += totalA;
        if (tid == 0) pfx[0] = 0;
        pfx[tid + 1] = A;        // pfx[1..64]
        pfx[tid + 65] = B;       // pfx[65..128]
    }
    __syncthreads();
}

// =========================== count phase ===================================

__global__ void count_group_kernel(const int* __restrict__ dst,
                                   int* __restrict__ priv,
                                   int n_nodes, int n_edges, int egroup) {
    int g = blockIdx.x & (NG - 1);
    int c = blockIdx.x >> 3;
    int nchunks = gridDim.x >> 3;
    int ebeg = g * egroup;
    int eend = ebeg + egroup; if (eend > n_edges) eend = n_edges;
    int* cnt = priv + (size_t)g * n_nodes;
    int stride = nchunks * blockDim.x;
    for (int e = ebeg + c * blockDim.x + threadIdx.x; e < eend; e += stride) {
        atomicAdd(&cnt[dst[e]], 1);
    }
}

__global__ void hist_part_kernel(const int* __restrict__ dst,
                                 int* __restrict__ counts,
                                 int n_edges, int nodes_per_range) {
    int r = blockIdx.x & (NR - 1);
    int c = blockIdx.x / NR;
    int nchunks = gridDim.x / NR;
    int lo = r * nodes_per_range;
    int hi = lo + nodes_per_range;
    int stride = nchunks * blockDim.x;
    for (int e = c * blockDim.x + threadIdx.x; e < n_edges; e += stride) {
        int d = dst[e];
        if (d >= lo && d < hi) atomicAdd(&counts[d], 1);
    }
}

// =========================== scan phase (one dispatch) =====================

// main: cross-group exclusive prefix (priv in place) + tile-local block scan.
__global__ void scanA_fused_kernel(int* __restrict__ priv,
                                   int* __restrict__ offsets,
                                   int* __restrict__ blocksums, int n_nodes) {
    __shared__ int smem16[16];
    int i = blockIdx.x * SCAN_BLOCK + threadIdx.x;
    int total = 0;
    if (i < n_nodes) {
        int run = 0;
        #pragma unroll
        for (int g = 0; g < NG; ++g) {
            size_t idx = (size_t)g * n_nodes + i;
            int t = priv[idx];
            priv[idx] = run;
            run += t;
        }
        total = run;
    }
    int excl = block_scan_excl_1024(total, smem16);
    if (i < n_nodes) offsets[i] = excl;                 // tile-local
    if (threadIdx.x == SCAN_BLOCK - 1) blocksums[blockIdx.x] = excl + total;  // raw
}

// fallback: scan plain counts array
__global__ void scanA_plain_kernel(const int* __restrict__ counts,
                                   int* __restrict__ offsets,
                                   int* __restrict__ blocksums, int n) {
    __shared__ int smem16[16];
    int i = blockIdx.x * SCAN_BLOCK + threadIdx.x;
    int v = (i < n) ? counts[i] : 0;
    int e = block_scan_excl_1024(v, smem16);
    if (i < n) offsets[i] = e;                          // tile-local
    if (threadIdx.x == SCAN_BLOCK - 1) blocksums[blockIdx.x] = e + v;   // raw
}

// =========================== scatter phase =================================

// block (r,g,c): r -> XCD r. pos = tile-local offset + LDS tile base + cursor.
__global__ void scatter_rg_kernel(const int* __restrict__ src,
                                  const int* __restrict__ dst,
                                  const int* __restrict__ offsets,
                                  const int* __restrict__ blocksums,
                                  int* __restrict__ priv,
                                  int* __restrict__ sorted_src,
                                  int n_nodes, int n_edges, int egroup,
                                  int nodes_per_range, int ntiles) {
    __shared__ int pfx[130];
    build_pfx_lds(blocksums, ntiles, pfx);

    int r = blockIdx.x & (NR - 1);
    int g = (blockIdx.x >> 3) & (NG - 1);
    int c = blockIdx.x >> 6;
    int nchunks = gridDim.x >> 6;
    int lo = r * nodes_per_range;
    int hi = lo + nodes_per_range;
    int ebeg = g * egroup;
    int eend = ebeg + egroup; if (eend > n_edges) eend = n_edges;
    int* cur = priv + (size_t)g * n_nodes;
    int stride = nchunks * blockDim.x;
    for (int e = ebeg + c * blockDim.x + threadIdx.x; e < eend; e += stride) {
        int d = dst[e];
        if (d >= lo && d < hi) {
            int pos = offsets[d] + pfx[d >> 10] + atomicAdd(&cur[d], 1);
            sorted_src[pos] = src[e];
        }
    }
}

// fallback scatter: separate cursor array (zeroed), single counts-free path
__global__ void scatter_fb_kernel(const int* __restrict__ src,
                                  const int* __restrict__ dst,
                                  const int* __restrict__ offsets,
                                  const int* __restrict__ blocksums,
                                  int* __restrict__ cursor,
                                  int* __restrict__ sorted_src,
                                  int n_edges, int nodes_per_range, int ntiles) {
    __shared__ int pfx[130];
    build_pfx_lds(blocksums, ntiles, pfx);

    int r = blockIdx.x & (NR - 1);
    int c = blockIdx.x / NR;
    int nchunks = gridDim.x / NR;
    int lo = r * nodes_per_range;
    int hi = lo + nodes_per_range;
    int stride = nchunks * blockDim.x;
    for (int e = c * blockDim.x + threadIdx.x; e < n_edges; e += stride) {
        int d = dst[e];
        if (d >= lo && d < hi) {
            int pos = offsets[d] + pfx[d >> 10] + atomicAdd(&cursor[d], 1);
            sorted_src[pos] = src[e];
        }
    }
}

// ============================== pull phase =================================

// one wave per node; 4 groups x 16 lanes, float4 gathers, 2-deep unroll.
// Tile bases reconstructed per wave via masked shuffle-reduction (no LDS).
__global__ void pull_max_kernel(const float* __restrict__ inp,
                                const int* __restrict__ offsets,
                                const int* __restrict__ blocksums,
                                const int* __restrict__ sorted_src,
                                float* __restrict__ out,
                                int n_nodes, int n_edges) {
    int gtid = blockIdx.x * blockDim.x + threadIdx.x;
    int node = gtid >> 6;
    if (node >= n_nodes) return;
    int lane = threadIdx.x & 63;
    int g = lane >> 4;
    int l = lane & 15;

    // exclusive prefix of blocksums up to tile t, via 64-lane masked reduce
    int t = node >> 10;
    int contrib = ((lane < t) ? blocksums[lane] : 0) +
                  ((lane + 64 < t) ? blocksums[lane + 64] : 0);
    #pragma unroll
    for (int d = 32; d > 0; d >>= 1) contrib += __shfl_xor(contrib, d, 64);
    int base = contrib;                       // sum of blocksums[0..t-1]

    int beg = offsets[node] + base;
    int end;
    if (node + 1 == n_nodes) {
        end = n_edges;
    } else {
        int t2 = (node + 1) >> 10;
        int base2 = (t2 == t) ? base : base + blocksums[t];
        end = offsets[node + 1] + base2;
    }

    const float4* inp4 = reinterpret_cast<const float4*>(inp);
    float4 own = inp4[(size_t)node * 16 + l];

    float4 m;
    m.x = -INFINITY; m.y = -INFINITY; m.z = -INFINITY; m.w = -INFINITY;
    int j = beg + g;
    for (; j + 4 < end; j += 8) {
        int s0 = sorted_src[j];
        int s1 = sorted_src[j + 4];
        float4 v0 = inp4[(size_t)s0 * 16 + l];
        float4 v1 = inp4[(size_t)s1 * 16 + l];
        m.x = fmaxf(m.x, fmaxf(v0.x, v1.x));
        m.y = fmaxf(m.y, fmaxf(v0.y, v1.y));
        m.z = fmaxf(m.z, fmaxf(v0.z, v1.z));
        m.w = fmaxf(m.w, fmaxf(v0.w, v1.w));
    }
    if (j < end) {
        int s = sorted_src[j];
        float4 v = inp4[(size_t)s * 16 + l];
        m.x = fmaxf(m.x, v.x);
        m.y = fmaxf(m.y, v.y);
        m.z = fmaxf(m.z, v.z);
        m.w = fmaxf(m.w, v.w);
    }
    m.x = fmaxf(m.x, __shfl_xor(m.x, 16, 64));
    m.y = fmaxf(m.y, __shfl_xor(m.y, 16, 64));
    m.z = fmaxf(m.z, __shfl_xor(m.z, 16, 64));
    m.w = fmaxf(m.w, __shfl_xor(m.w, 16, 64));
    m.x = fmaxf(m.x, __shfl_xor(m.x, 32, 64));
    m.y = fmaxf(m.y, __shfl_xor(m.y, 32, 64));
    m.z = fmaxf(m.z, __shfl_xor(m.z, 32, 64));
    m.w = fmaxf(m.w, __shfl_xor(m.w, 32, 64));

    if (beg == end) m = own;   // isolated node keeps own feature

    float4* out4 = reinterpret_cast<float4*>(out);
    if (lane < 16) {
        out4[(size_t)node * 32 + l] = own;
    } else if (lane < 32) {
        out4[(size_t)node * 32 + 16 + l] = m;
    }
}

// ===========================================================================

extern "C" void kernel_launch(void* const* d_in, const int* in_sizes, int n_in,
                              void* d_out, int out_size, void* d_ws, size_t ws_size,
                              hipStream_t stream) {
    const float* inp = (const float*)d_in[0];
    const int* src = (const int*)d_in[1];
    const int* dst = (const int*)d_in[2];
    float* out = (float*)d_out;

    int n_nodes = in_sizes[0] / D_FEAT;
    int n_edges = in_sizes[1];

    int ntiles = (n_nodes + SCAN_BLOCK - 1) / SCAN_BLOCK;   // 98 for 100K
    int nodes_per_range = (n_nodes + NR - 1) / NR;
    int egroup = (n_edges + NG - 1) / NG;

    int* ws = (int*)d_ws;
    size_t need_main = ((size_t)NG * n_nodes + (size_t)(n_nodes + 1) + 128 +
                        (size_t)n_edges) * sizeof(int);

    if (ws_size >= need_main && ntiles <= 128) {
        // ------------------- main path (5 dispatches) -------------------
        int* priv = ws;                                        // NG*n
        int* offsets = ws + (size_t)NG * n_nodes;              // n+1
        int* blocksums = offsets + n_nodes + 1;                // 128
        int* sorted_src = blocksums + 128;                     // E

        hipMemsetAsync(priv, 0, (size_t)NG * n_nodes * sizeof(int), stream);
        count_group_kernel<<<NG * 256, 256, 0, stream>>>(dst, priv, n_nodes,
                                                         n_edges, egroup);
        scanA_fused_kernel<<<ntiles, SCAN_BLOCK, 0, stream>>>(priv, offsets,
                                                              blocksums, n_nodes);
        scatter_rg_kernel<<<NR * NG * 32, 256, 0, stream>>>(src, dst, offsets,
                                                            blocksums, priv,
                                                            sorted_src,
                                                            n_nodes, n_edges,
                                                            egroup, nodes_per_range,
                                                            ntiles);
        {
            int total = n_nodes * 64;
            pull_max_kernel<<<(total + 255) / 256, 256, 0, stream>>>(
                inp, offsets, blocksums, sorted_src, out, n_nodes, n_edges);
        }
    } else {
        // ------------------- fallback path (5 dispatches) -------------------
        int* counts = ws;                                      // n
        int* cursor = ws + n_nodes;                            // n
        int* offsets = cursor + n_nodes;                       // n+1
        int* blocksums = offsets + n_nodes + 1;                // 128
        int* sorted_src = blocksums + 128;                     // E

        hipMemsetAsync(counts, 0, 2 * (size_t)n_nodes * sizeof(int), stream);
        hist_part_kernel<<<NR * 256, 256, 0, stream>>>(dst, counts, n_edges,
                                                       nodes_per_range);
        scanA_plain_kernel<<<ntiles, SCAN_BLOCK, 0, stream>>>(counts, offsets,
                                                              blocksums, n_nodes);
        scatter_fb_kernel<<<NR * 256, 256, 0, stream>>>(src, dst, offsets,
                                                        blocksums, cursor,
                                                        sorted_src, n_edges,
                                                        nodes_per_range, ntiles);
        {
            int total = n_nodes * 64;
            pull_max_kernel<<<(total + 255) / 256, 256, 0, stream>>>(
                inp, offsets, blocksums, sorted_src, out, n_nodes, n_edges);
        }
    }
}